// Round 9
// baseline (111.154 us; speedup 1.0000x reference)
//
#include <hip/hip_runtime.h>
#include <math.h>

typedef float f4v __attribute__((ext_vector_type(4)));
typedef float f2v __attribute__((ext_vector_type(2)));

// Problem constants (from reference setup_inputs)
constexpr int Bn = 4, Tn = 1000, Fn = 257, Cn = 6, Dn = 2048, On = 2;
constexpr int BTn = Bn * Tn;                      // 4000
constexpr double DEG2RAD = 0.017453292519943295;  // pi/180 in double

// Output segment offsets (in floats) within d_out
constexpr size_t OUT0_F = (size_t)BTn * Fn * Cn * 2;  // 12,336,000
constexpr size_t OUT1_F = (size_t)BTn * Fn * 2;       //  2,056,000

// Workspace layout (bytes) -- only tables + ind now
constexpr size_t TAB_BYTES  = (size_t)4 * Dn * sizeof(double);   // 65,536 (SoA [4][D])
constexpr size_t BTT_PAD    = 131072;                            // 4000*4 doubles padded
constexpr size_t IND_BYTES  = 16384;                             // 4000 ints, padded
constexpr size_t WS_NEEDED  = TAB_BYTES + BTT_PAD + IND_BYTES;

// ---------------------------------------------------------------------------
// K0: trig tables in double (verified bit-exact vs np in R4/R7).
// ---------------------------------------------------------------------------
__global__ __launch_bounds__(256) void build_tables(const float2* __restrict__ dirs,
                                                    const float* __restrict__ tdoa,
                                                    double* __restrict__ tab,
                                                    double* __restrict__ bttab) {
    int id = blockIdx.x * 256 + threadIdx.x;
    if (id < Dn) {
        float2 dr = dirs[id];
        double d0 = (double)dr.x, d1 = (double)dr.y;
        tab[0 * Dn + id] = cos(d0);
        tab[1 * Dn + id] = sin(d0);
        tab[2 * Dn + id] = cos(d1);
        tab[3 * Dn + id] = sin(d1);
    } else if (id < Dn + BTn) {
        int bt = id - Dn;
        double t0 = DEG2RAD * (double)tdoa[bt * 2 + 0];
        double t1 = DEG2RAD * (double)tdoa[bt * 2 + 1];
        bttab[bt * 4 + 0] = cos(t0);
        bttab[bt * 4 + 1] = sin(t0);
        bttab[bt * 4 + 2] = cos(t1);
        bttab[bt * 4 + 3] = sin(t1);
    }
}

// ---------------------------------------------------------------------------
// K1: argmin over direction codebook (verified passing in R7, unchanged).
// ---------------------------------------------------------------------------
__global__ __launch_bounds__(256) void argmin_lds(const double* __restrict__ bttab,
                                                  const double* __restrict__ tab,
                                                  int* __restrict__ ind) {
    __shared__ double s_cd0[Dn];
    __shared__ double s_sd0[Dn];
    __shared__ double s_cd1[Dn];
    __shared__ double s_sd1[Dn];
    const int t = threadIdx.x;
    #pragma unroll
    for (int k = 0; k < Dn / 256; ++k) {
        int d = t + 256 * k;
        s_cd0[d] = tab[0 * Dn + d];
        s_sd0[d] = tab[1 * Dn + d];
        s_cd1[d] = tab[2 * Dn + d];
        s_sd1[d] = tab[3 * Dn + d];
    }
    __syncthreads();
    const int w = t >> 6, lane = t & 63;
    #pragma unroll
    for (int s = 0; s < 4; ++s) {
        const int bt = blockIdx.x * 16 + w * 4 + s;
        double ct0 = bttab[bt * 4 + 0], st0 = bttab[bt * 4 + 1];
        double ct1 = bttab[bt * 4 + 2], st1 = bttab[bt * 4 + 3];
        double best = 1e300;
        int bidx = 0;
        for (int i = 0; i < Dn / 256; ++i) {
            const int d0 = lane + 256 * i;
            double a[4];
            #pragma unroll
            for (int k = 0; k < 4; ++k) {
                int d = d0 + 64 * k;
                double u  = ct1 * s_cd1[d];
                double m1 = 1.0 - (u + st1 * s_sd1[d]);
                double m0 = 1.0 - (ct0 * s_cd0[d] + st0 * s_sd0[d]);
                a[k] = m1 + u * m0;
            }
            #pragma unroll
            for (int k = 0; k < 4; ++k) {
                int d = d0 + 64 * k;
                if (a[k] < best) { best = a[k]; bidx = d; }
            }
        }
        #pragma unroll
        for (int off = 32; off > 0; off >>= 1) {
            double ov = __shfl_down(best, off);
            int oi = __shfl_down(bidx, off);
            if (ov < best || (ov == best && oi < bidx)) { best = ov; bidx = oi; }
        }
        if (lane == 0) ind[bt] = bidx;
    }
}

// ---------------------------------------------------------------------------
// K2: fused tile-gather-multiply for wc (out1) and wd (out0).
// Block = (d-chunk of 64, f-chunk of 8). Stages both weight tiles in LDS,
// scans ind[] for bts whose selected dir lies in this d-chunk (~125 avg),
// then per match reads the X slice once and writes final out0/out1 directly.
// No workspace round-trip; X and weights are each read exactly once.
// ---------------------------------------------------------------------------
constexpr int FCH = 8;        // f per chunk
constexpr int RWS = FCH * Cn; // 48 rows

__global__ __launch_bounds__(256) void fuse_cd(
    const float* __restrict__ Xr, const float* __restrict__ Xi,
    const int* __restrict__ ind,
    const float* __restrict__ wcr, const float* __restrict__ wci,
    const float* __restrict__ wdr, const float* __restrict__ wdi,
    float* __restrict__ out0, float* __restrict__ out1) {
    __shared__ f2v tc[RWS][66];   // (re,im), row = fi*6+c, col = d-local
    __shared__ f2v td[RWS][66];
    __shared__ int lst[BTn];      // (bt<<6)|dl  (worst case: all bts here)
    __shared__ int cnt;
    const int d0 = blockIdx.x * 64;
    const int f0 = blockIdx.y * FCH;
    const int t = threadIdx.x;
    if (t == 0) cnt = 0;
    // need cnt=0 visible before LDS atomics below
    __syncthreads();

    // ---- stage wc & wd tiles: 2 pairs x 48 rows x 16 float4 = 6 x 256 ----
    // 768 items per pair = exactly 3 iterations of 256, so pair = (j<3)?0:1.
    #pragma unroll
    for (int j = 0; j < 6; ++j) {
        int idx = j * 256 + t;
        const int pair = (j < 3) ? 0 : 1;
        int k = idx - pair * 768;     // 0..767 within pair
        int r = k >> 4, q4 = k & 15;
        int fi = r / Cn, c = r - fi * Cn;
        int f = f0 + fi;
        if (f < Fn) {
            size_t s = (size_t)(c * Fn + f) * Dn + d0 + 4 * q4;
            f4v vr = __builtin_nontemporal_load((const f4v*)((pair ? wdr : wcr) + s));
            f4v vi = __builtin_nontemporal_load((const f4v*)((pair ? wdi : wci) + s));
            f4v* trow = (f4v*)&(pair ? td : tc)[r][0];
            f4v lo = {vr[0], vi[0], vr[1], vi[1]};
            f4v hi = {vr[2], vi[2], vr[3], vi[3]};
            trow[2 * q4]     = lo;
            trow[2 * q4 + 1] = hi;
        }
    }
    // ---- scan ind for matches in [d0, d0+64) ----
    #pragma unroll
    for (int k = 0; k < (BTn + 255) / 256; ++k) {
        int bt = k * 256 + t;
        if (bt < BTn) {
            int dv = ind[bt] - d0;
            if ((unsigned)dv < 64u) {
                int p = atomicAdd(&cnt, 1);
                lst[p] = (bt << 6) | dv;
            }
        }
    }
    __syncthreads();

    // ---- process matches: item = (m, fi) ----
    const int items = cnt * FCH;
    for (int base = 0; base < items; base += 256) {
        int it = base + t;
        if (it < items) {
            int m = it >> 3, fi = it & 7;
            int e = lst[m];
            int bt = e >> 6, dl = e & 63;
            int f = f0 + fi;
            if (f < Fn) {
                size_t xb = ((size_t)bt * Fn + f) * Cn;   // float index
                const f2v* xr2 = (const f2v*)(Xr + xb);
                const f2v* xi2 = (const f2v*)(Xi + xb);
                f2v xra = __builtin_nontemporal_load(xr2);
                f2v xrb = __builtin_nontemporal_load(xr2 + 1);
                f2v xrc = __builtin_nontemporal_load(xr2 + 2);
                f2v xia = __builtin_nontemporal_load(xi2);
                f2v xib = __builtin_nontemporal_load(xi2 + 1);
                f2v xic = __builtin_nontemporal_load(xi2 + 2);
                float xr[Cn] = {xra[0], xra[1], xrb[0], xrb[1], xrc[0], xrc[1]};
                float xi[Cn] = {xia[0], xia[1], xib[0], xib[1], xic[0], xic[1]};
                float o0[Cn * 2];
                float accr = 0.f, acci = 0.f;
                const int rb = fi * Cn;
                #pragma unroll
                for (int c = 0; c < Cn; ++c) {
                    f2v wcv = tc[rb + c][dl];
                    f2v wdv = td[rb + c][dl];
                    o0[2 * c]     = wdv[0] * xr[c] - wdv[1] * xi[c];
                    o0[2 * c + 1] = wdv[0] * xi[c] + wdv[1] * xr[c];
                    accr += wcv[0] * xr[c] - wcv[1] * xi[c];
                    acci += wcv[0] * xi[c] + wcv[1] * xr[c];
                }
                f4v* ob = (f4v*)(out0 + xb * 2);          // 48B-multiple -> 16B aligned
                f4v p0 = {o0[0], o0[1], o0[2], o0[3]};
                f4v p1 = {o0[4], o0[5], o0[6], o0[7]};
                f4v p2 = {o0[8], o0[9], o0[10], o0[11]};
                __builtin_nontemporal_store(p0, ob);
                __builtin_nontemporal_store(p1, ob + 1);
                __builtin_nontemporal_store(p2, ob + 2);
                f2v o1 = {accr, acci};
                __builtin_nontemporal_store(o1, (f2v*)out1 + ((size_t)bt * Fn + f));
            }
        }
    }
}

// ---------------------------------------------------------------------------
// K3: fused tile-gather for w_binaural -> out2 (pure panel copy).
// Block = (d-chunk 64, f-chunk 24). Rows = fi*2+o.
// ---------------------------------------------------------------------------
constexpr int FCB = 24;
constexpr int RWB = FCB * On;  // 48 rows

__global__ __launch_bounds__(256) void fuse_b(
    const int* __restrict__ ind,
    const float* __restrict__ wbr, const float* __restrict__ wbi,
    float* __restrict__ out2) {
    __shared__ f2v tb[RWB][66];
    __shared__ int lst[BTn];
    __shared__ int cnt;
    const int d0 = blockIdx.x * 64;
    const int f0 = blockIdx.y * FCB;
    const int t = threadIdx.x;
    if (t == 0) cnt = 0;
    __syncthreads();

    #pragma unroll
    for (int j = 0; j < 3; ++j) {   // 48 rows x 16 f4 = 768 = 3 x 256
        int idx = j * 256 + t;
        int r = idx >> 4, q4 = idx & 15;
        int fi = r >> 1, o = r & 1;
        int f = f0 + fi;
        if (f < Fn) {
            size_t s = (size_t)(o * Fn + f) * Dn + d0 + 4 * q4;
            f4v vr = __builtin_nontemporal_load((const f4v*)(wbr + s));
            f4v vi = __builtin_nontemporal_load((const f4v*)(wbi + s));
            f4v* trow = (f4v*)&tb[r][0];
            f4v lo = {vr[0], vi[0], vr[1], vi[1]};
            f4v hi = {vr[2], vi[2], vr[3], vi[3]};
            trow[2 * q4]     = lo;
            trow[2 * q4 + 1] = hi;
        }
    }
    #pragma unroll
    for (int k = 0; k < (BTn + 255) / 256; ++k) {
        int bt = k * 256 + t;
        if (bt < BTn) {
            int dv = ind[bt] - d0;
            if ((unsigned)dv < 64u) {
                int p = atomicAdd(&cnt, 1);
                lst[p] = (bt << 6) | dv;
            }
        }
    }
    __syncthreads();

    const int items = cnt * FCB;
    for (int base = 0; base < items; base += 256) {
        int it = base + t;
        if (it < items) {
            int m = it / FCB, fi = it - m * FCB;
            int e = lst[m];
            int bt = e >> 6, dl = e & 63;
            int f = f0 + fi;
            if (f < Fn) {
                f2v a = tb[fi * 2][dl];      // o=0 (re,im)
                f2v b = tb[fi * 2 + 1][dl];  // o=1 (re,im)
                f4v o2 = {a[0], a[1], b[0], b[1]};
                __builtin_nontemporal_store(o2, (f4v*)out2 + ((size_t)bt * Fn + f));
            }
        }
    }
}

// Fallback (no workspace): direct strided gather, per-block argmin
__global__ __launch_bounds__(256) void main_direct(
    const float* __restrict__ Xr, const float* __restrict__ Xi,
    const float* __restrict__ tdoa, const float2* __restrict__ dirs,
    const float* __restrict__ wcr, const float* __restrict__ wci,
    const float* __restrict__ wdr, const float* __restrict__ wdi,
    const float* __restrict__ wbr, const float* __restrict__ wbi,
    float2* __restrict__ out0, float2* __restrict__ out1, float2* __restrict__ out2) {
    const int bt = blockIdx.x;
    const int tid = threadIdx.x;
    __shared__ double sv[256];
    __shared__ int si[256];

    double t0 = DEG2RAD * (double)tdoa[bt * 2 + 0];
    double t1 = DEG2RAD * (double)tdoa[bt * 2 + 1];
    double ct1 = cos(t1);
    double best = 1e300;
    int bidx = 0;
    for (int d = tid; d < Dn; d += 256) {
        float2 dr = dirs[d];
        double s1 = sin(0.5 * (t1 - (double)dr.y));
        double s2 = sin(0.5 * (t0 - (double)dr.x));
        double a = s1 * s1 + ct1 * cos((double)dr.y) * (s2 * s2);
        if (a < best) { best = a; bidx = d; }
    }
    sv[tid] = best; si[tid] = bidx;
    __syncthreads();
    for (int s = 128; s > 0; s >>= 1) {
        if (tid < s) {
            double v = sv[tid + s]; int j = si[tid + s];
            if (v < sv[tid] || (v == sv[tid] && j < si[tid])) { sv[tid] = v; si[tid] = j; }
        }
        __syncthreads();
    }
    const int dsel = si[0];
    const size_t base = (size_t)bt * Fn * Cn;

    for (int f = tid; f < Fn; f += 256) {
        const int fc = f * Cn;
        float accr = 0.f, acci = 0.f;
        #pragma unroll
        for (int c = 0; c < Cn; ++c) {
            float xr = Xr[base + fc + c], xi = Xi[base + fc + c];
            size_t wo = (size_t)(c * Fn + f) * Dn + dsel;
            float a_ = wdr[wo], b_ = wdi[wo];
            out0[base + fc + c] = make_float2(a_ * xr - b_ * xi, a_ * xi + b_ * xr);
            float p = wcr[wo], q = wci[wo];
            accr += p * xr - q * xi;
            acci += p * xi + q * xr;
        }
        out1[(size_t)bt * Fn + f] = make_float2(accr, acci);
        #pragma unroll
        for (int o = 0; o < On; ++o) {
            size_t wo = (size_t)(o * Fn + f) * Dn + dsel;
            out2[((size_t)bt * Fn + f) * On + o] = make_float2(wbr[wo], wbi[wo]);
        }
    }
}

extern "C" void kernel_launch(void* const* d_in, const int* in_sizes, int n_in,
                              void* d_out, int out_size, void* d_ws, size_t ws_size,
                              hipStream_t stream) {
    const float* Xr   = (const float*)d_in[0];
    const float* Xi   = (const float*)d_in[1];
    const float* tdoa = (const float*)d_in[2];
    const float2* dirs = (const float2*)d_in[3];
    const float* wcr = (const float*)d_in[4];
    const float* wci = (const float*)d_in[5];
    const float* wdr = (const float*)d_in[6];
    const float* wdi = (const float*)d_in[7];
    const float* wbr = (const float*)d_in[8];
    const float* wbi = (const float*)d_in[9];

    float* out = (float*)d_out;

    if (ws_size >= WS_NEEDED) {
        char* ws = (char*)d_ws;
        double* tab   = (double*)ws;
        double* bttab = (double*)(ws + TAB_BYTES);
        int* ind  = (int*)(ws + TAB_BYTES + BTT_PAD);

        build_tables<<<(Dn + BTn + 255) / 256, 256, 0, stream>>>(dirs, tdoa, tab, bttab);
        argmin_lds<<<BTn / 16, 256, 0, stream>>>(bttab, tab, ind);
        dim3 gcd(Dn / 64, (Fn + FCH - 1) / FCH);   // 32 x 33
        fuse_cd<<<gcd, 256, 0, stream>>>(Xr, Xi, ind, wcr, wci, wdr, wdi,
                                         out, out + OUT0_F);
        dim3 gb(Dn / 64, (Fn + FCB - 1) / FCB);    // 32 x 11
        fuse_b<<<gb, 256, 0, stream>>>(ind, wbr, wbi, out + OUT0_F + OUT1_F);
    } else {
        main_direct<<<BTn, 256, 0, stream>>>(Xr, Xi, tdoa, dirs,
                                             wcr, wci, wdr, wdi, wbr, wbi,
                                             (float2*)out,
                                             (float2*)(out + OUT0_F),
                                             (float2*)(out + OUT0_F + OUT1_F));
    }
}

// Round 10
// 69.665 us; speedup vs baseline: 1.5956x; 1.5956x over previous
//
#include <hip/hip_runtime.h>
#include <math.h>

typedef float f4v __attribute__((ext_vector_type(4)));
typedef float f2v __attribute__((ext_vector_type(2)));

// Problem constants (from reference setup_inputs)
constexpr int Bn = 4, Tn = 1000, Fn = 257, Cn = 6, Dn = 2048, On = 2;
constexpr int BTn = Bn * Tn;                      // 4000
constexpr double DEG2RAD = 0.017453292519943295;  // pi/180 in double

// Output segment offsets (in floats) within d_out
constexpr size_t OUT0_F = (size_t)BTn * Fn * Cn * 2;  // 12,336,000
constexpr size_t OUT1_F = (size_t)BTn * Fn * 2;       //  2,056,000

// d-chunking for the fused gather kernels
constexpr int DCH = 32;          // dirs per chunk
constexpr int NCH = Dn / DCH;    // 64 chunks

// Workspace layout (bytes)
constexpr size_t TAB_BYTES  = (size_t)4 * Dn * sizeof(double);   // 65,536
constexpr size_t BTT_PAD    = 131072;                            // 4000*4 doubles padded
constexpr size_t IND_BYTES  = 16384;                             // 4000 ints padded
constexpr size_t BOFF_BYTES = 4096;                              // 65 ints padded
constexpr size_t BENT_BYTES = 16384;                             // 4000 ints padded
constexpr size_t WS_NEEDED  = TAB_BYTES + BTT_PAD + IND_BYTES + BOFF_BYTES + BENT_BYTES;

// ---------------------------------------------------------------------------
// K0: trig tables in double (verified bit-exact vs np in R4/R7).
// ---------------------------------------------------------------------------
__global__ __launch_bounds__(256) void build_tables(const float2* __restrict__ dirs,
                                                    const float* __restrict__ tdoa,
                                                    double* __restrict__ tab,
                                                    double* __restrict__ bttab) {
    int id = blockIdx.x * 256 + threadIdx.x;
    if (id < Dn) {
        float2 dr = dirs[id];
        double d0 = (double)dr.x, d1 = (double)dr.y;
        tab[0 * Dn + id] = cos(d0);
        tab[1 * Dn + id] = sin(d0);
        tab[2 * Dn + id] = cos(d1);
        tab[3 * Dn + id] = sin(d1);
    } else if (id < Dn + BTn) {
        int bt = id - Dn;
        double t0 = DEG2RAD * (double)tdoa[bt * 2 + 0];
        double t1 = DEG2RAD * (double)tdoa[bt * 2 + 1];
        bttab[bt * 4 + 0] = cos(t0);
        bttab[bt * 4 + 1] = sin(t0);
        bttab[bt * 4 + 2] = cos(t1);
        bttab[bt * 4 + 3] = sin(t1);
    }
}

// ---------------------------------------------------------------------------
// K1: argmin over direction codebook (verified passing R7/R9, unchanged).
// ---------------------------------------------------------------------------
__global__ __launch_bounds__(256) void argmin_lds(const double* __restrict__ bttab,
                                                  const double* __restrict__ tab,
                                                  int* __restrict__ ind) {
    __shared__ double s_cd0[Dn];
    __shared__ double s_sd0[Dn];
    __shared__ double s_cd1[Dn];
    __shared__ double s_sd1[Dn];
    const int t = threadIdx.x;
    #pragma unroll
    for (int k = 0; k < Dn / 256; ++k) {
        int d = t + 256 * k;
        s_cd0[d] = tab[0 * Dn + d];
        s_sd0[d] = tab[1 * Dn + d];
        s_cd1[d] = tab[2 * Dn + d];
        s_sd1[d] = tab[3 * Dn + d];
    }
    __syncthreads();
    const int w = t >> 6, lane = t & 63;
    #pragma unroll
    for (int s = 0; s < 4; ++s) {
        const int bt = blockIdx.x * 16 + w * 4 + s;
        double ct0 = bttab[bt * 4 + 0], st0 = bttab[bt * 4 + 1];
        double ct1 = bttab[bt * 4 + 2], st1 = bttab[bt * 4 + 3];
        double best = 1e300;
        int bidx = 0;
        for (int i = 0; i < Dn / 256; ++i) {
            const int d0 = lane + 256 * i;
            double a[4];
            #pragma unroll
            for (int k = 0; k < 4; ++k) {
                int d = d0 + 64 * k;
                double u  = ct1 * s_cd1[d];
                double m1 = 1.0 - (u + st1 * s_sd1[d]);
                double m0 = 1.0 - (ct0 * s_cd0[d] + st0 * s_sd0[d]);
                a[k] = m1 + u * m0;
            }
            #pragma unroll
            for (int k = 0; k < 4; ++k) {
                int d = d0 + 64 * k;
                if (a[k] < best) { best = a[k]; bidx = d; }
            }
        }
        #pragma unroll
        for (int off = 32; off > 0; off >>= 1) {
            double ov = __shfl_down(best, off);
            int oi = __shfl_down(bidx, off);
            if (ov < best || (ov == best && oi < bidx)) { best = ov; bidx = oi; }
        }
        if (lane == 0) ind[bt] = bidx;
    }
}

// ---------------------------------------------------------------------------
// K2: bucket bts by 32-wide d-chunk. One block. Order within a bucket is
// nondeterministic (atomics) but every output element is produced by exactly
// one (bt,f) work item -> results are deterministic.
// ---------------------------------------------------------------------------
__global__ __launch_bounds__(256) void bucket_bts(const int* __restrict__ ind,
                                                  int* __restrict__ boff,
                                                  int* __restrict__ bent) {
    __shared__ int cnts[NCH];
    __shared__ int curs[NCH];
    const int t = threadIdx.x;
    if (t < NCH) cnts[t] = 0;
    __syncthreads();
    #pragma unroll
    for (int k = 0; k < (BTn + 255) / 256; ++k) {
        int bt = k * 256 + t;
        if (bt < BTn) atomicAdd(&cnts[ind[bt] >> 5], 1);
    }
    __syncthreads();
    if (t == 0) {
        int acc = 0;
        for (int i = 0; i < NCH; ++i) { curs[i] = acc; boff[i] = acc; acc += cnts[i]; }
        boff[NCH] = acc;
    }
    __syncthreads();
    #pragma unroll
    for (int k = 0; k < (BTn + 255) / 256; ++k) {
        int bt = k * 256 + t;
        if (bt < BTn) {
            int d = ind[bt];
            int p = atomicAdd(&curs[d >> 5], 1);
            bent[p] = (bt << 5) | (d & 31);
        }
    }
}

// ---------------------------------------------------------------------------
// K3: fused tile-gather-multiply for wc (out1) and wd (out0).
// Block = (d-chunk of 32, f-chunk of 8). 26 KB LDS -> ~5 blocks/CU.
// Match list comes precomputed from bucket_bts (no scan, no LDS list).
// Outputs use normal cached stores so L2 merges straddled 64B lines.
// ---------------------------------------------------------------------------
constexpr int FCH = 8;        // f per chunk
constexpr int RWS = FCH * Cn; // 48 rows

__global__ __launch_bounds__(256) void fuse_cd(
    const float* __restrict__ Xr, const float* __restrict__ Xi,
    const int* __restrict__ boff, const int* __restrict__ bent,
    const float* __restrict__ wcr, const float* __restrict__ wci,
    const float* __restrict__ wdr, const float* __restrict__ wdi,
    float* __restrict__ out0, float* __restrict__ out1) {
    __shared__ f2v tc[RWS][34];   // (re,im); row = fi*6+c; col = d-local; 272B row (16B aligned)
    __shared__ f2v td[RWS][34];
    const int d0 = blockIdx.x * DCH;
    const int f0 = blockIdx.y * FCH;
    const int t = threadIdx.x;

    // ---- stage wc & wd tiles: 2 pairs x 48 rows x 8 float4 = 768 = 3 x 256 ----
    #pragma unroll
    for (int j = 0; j < 3; ++j) {
        int idx = j * 256 + t;
        const int pair = (idx >= 384) ? 1 : 0;   // pair boundary = wave boundary
        int k = idx - pair * 384;                // 0..383
        int r = k >> 3, q4 = k & 7;
        int fi = r / Cn, c = r - fi * Cn;
        int f = f0 + fi;
        if (f < Fn) {
            size_t s = (size_t)(c * Fn + f) * Dn + d0 + 4 * q4;
            f4v vr = __builtin_nontemporal_load((const f4v*)((pair ? wdr : wcr) + s));
            f4v vi = __builtin_nontemporal_load((const f4v*)((pair ? wdi : wci) + s));
            f4v* trow = (f4v*)&(pair ? td : tc)[r][0];
            f4v lo = {vr[0], vi[0], vr[1], vi[1]};
            f4v hi = {vr[2], vi[2], vr[3], vi[3]};
            trow[2 * q4]     = lo;
            trow[2 * q4 + 1] = hi;
        }
    }
    const int off = boff[blockIdx.x];
    const int cnt = boff[blockIdx.x + 1] - off;
    __syncthreads();

    // ---- process matches: item = (m, fi) ----
    const int items = cnt * FCH;
    for (int base = 0; base < items; base += 256) {
        int it = base + t;
        if (it < items) {
            int m = it >> 3, fi = it & 7;
            int e = bent[off + m];
            int bt = e >> 5, dl = e & 31;
            int f = f0 + fi;
            if (f < Fn) {
                size_t xb = ((size_t)bt * Fn + f) * Cn;   // float index
                const f2v* xr2 = (const f2v*)(Xr + xb);
                const f2v* xi2 = (const f2v*)(Xi + xb);
                f2v xra = xr2[0], xrb = xr2[1], xrc = xr2[2];
                f2v xia = xi2[0], xib = xi2[1], xic = xi2[2];
                float xr[Cn] = {xra[0], xra[1], xrb[0], xrb[1], xrc[0], xrc[1]};
                float xi[Cn] = {xia[0], xia[1], xib[0], xib[1], xic[0], xic[1]};
                float o0[Cn * 2];
                float accr = 0.f, acci = 0.f;
                const int rb = fi * Cn;
                #pragma unroll
                for (int c = 0; c < Cn; ++c) {
                    f2v wcv = tc[rb + c][dl];
                    f2v wdv = td[rb + c][dl];
                    o0[2 * c]     = wdv[0] * xr[c] - wdv[1] * xi[c];
                    o0[2 * c + 1] = wdv[0] * xi[c] + wdv[1] * xr[c];
                    accr += wcv[0] * xr[c] - wcv[1] * xi[c];
                    acci += wcv[0] * xi[c] + wcv[1] * xr[c];
                }
                f4v* ob = (f4v*)(out0 + xb * 2);          // 48B-multiple -> 16B aligned
                f4v p0 = {o0[0], o0[1], o0[2], o0[3]};
                f4v p1 = {o0[4], o0[5], o0[6], o0[7]};
                f4v p2 = {o0[8], o0[9], o0[10], o0[11]};
                ob[0] = p0; ob[1] = p1; ob[2] = p2;       // cached stores: L2 merges lines
                f2v o1 = {accr, acci};
                ((f2v*)out1)[(size_t)bt * Fn + f] = o1;
            }
        }
    }
}

// ---------------------------------------------------------------------------
// K4: fused tile-gather for w_binaural -> out2 (pure panel copy).
// Block = (d-chunk 32, f-chunk 24). Rows = fi*2+o. 13 KB LDS.
// ---------------------------------------------------------------------------
constexpr int FCB = 24;
constexpr int RWB = FCB * On;  // 48 rows

__global__ __launch_bounds__(256) void fuse_b(
    const int* __restrict__ boff, const int* __restrict__ bent,
    const float* __restrict__ wbr, const float* __restrict__ wbi,
    float* __restrict__ out2) {
    __shared__ f2v tb[RWB][34];
    const int d0 = blockIdx.x * DCH;
    const int f0 = blockIdx.y * FCB;
    const int t = threadIdx.x;

    #pragma unroll
    for (int j = 0; j < 2; ++j) {   // 48 rows x 8 f4 = 384 items
        int idx = j * 256 + t;
        if (idx < RWB * 8) {
            int r = idx >> 3, q4 = idx & 7;
            int fi = r >> 1, o = r & 1;
            int f = f0 + fi;
            if (f < Fn) {
                size_t s = (size_t)(o * Fn + f) * Dn + d0 + 4 * q4;
                f4v vr = __builtin_nontemporal_load((const f4v*)(wbr + s));
                f4v vi = __builtin_nontemporal_load((const f4v*)(wbi + s));
                f4v* trow = (f4v*)&tb[r][0];
                f4v lo = {vr[0], vi[0], vr[1], vi[1]};
                f4v hi = {vr[2], vi[2], vr[3], vi[3]};
                trow[2 * q4]     = lo;
                trow[2 * q4 + 1] = hi;
            }
        }
    }
    const int off = boff[blockIdx.x];
    const int cnt = boff[blockIdx.x + 1] - off;
    __syncthreads();

    const int items = cnt * FCB;
    for (int base = 0; base < items; base += 256) {
        int it = base + t;
        if (it < items) {
            int m = it / FCB, fi = it - m * FCB;
            int e = bent[off + m];
            int bt = e >> 5, dl = e & 31;
            int f = f0 + fi;
            if (f < Fn) {
                f2v a = tb[fi * 2][dl];      // o=0 (re,im)
                f2v b = tb[fi * 2 + 1][dl];  // o=1 (re,im)
                f4v o2 = {a[0], a[1], b[0], b[1]};
                ((f4v*)out2)[(size_t)bt * Fn + f] = o2;
            }
        }
    }
}

// Fallback (no workspace): direct strided gather, per-block argmin
__global__ __launch_bounds__(256) void main_direct(
    const float* __restrict__ Xr, const float* __restrict__ Xi,
    const float* __restrict__ tdoa, const float2* __restrict__ dirs,
    const float* __restrict__ wcr, const float* __restrict__ wci,
    const float* __restrict__ wdr, const float* __restrict__ wdi,
    const float* __restrict__ wbr, const float* __restrict__ wbi,
    float2* __restrict__ out0, float2* __restrict__ out1, float2* __restrict__ out2) {
    const int bt = blockIdx.x;
    const int tid = threadIdx.x;
    __shared__ double sv[256];
    __shared__ int si[256];

    double t0 = DEG2RAD * (double)tdoa[bt * 2 + 0];
    double t1 = DEG2RAD * (double)tdoa[bt * 2 + 1];
    double ct1 = cos(t1);
    double best = 1e300;
    int bidx = 0;
    for (int d = tid; d < Dn; d += 256) {
        float2 dr = dirs[d];
        double s1 = sin(0.5 * (t1 - (double)dr.y));
        double s2 = sin(0.5 * (t0 - (double)dr.x));
        double a = s1 * s1 + ct1 * cos((double)dr.y) * (s2 * s2);
        if (a < best) { best = a; bidx = d; }
    }
    sv[tid] = best; si[tid] = bidx;
    __syncthreads();
    for (int s = 128; s > 0; s >>= 1) {
        if (tid < s) {
            double v = sv[tid + s]; int j = si[tid + s];
            if (v < sv[tid] || (v == sv[tid] && j < si[tid])) { sv[tid] = v; si[tid] = j; }
        }
        __syncthreads();
    }
    const int dsel = si[0];
    const size_t base = (size_t)bt * Fn * Cn;

    for (int f = tid; f < Fn; f += 256) {
        const int fc = f * Cn;
        float accr = 0.f, acci = 0.f;
        #pragma unroll
        for (int c = 0; c < Cn; ++c) {
            float xr = Xr[base + fc + c], xi = Xi[base + fc + c];
            size_t wo = (size_t)(c * Fn + f) * Dn + dsel;
            float a_ = wdr[wo], b_ = wdi[wo];
            out0[base + fc + c] = make_float2(a_ * xr - b_ * xi, a_ * xi + b_ * xr);
            float p = wcr[wo], q = wci[wo];
            accr += p * xr - q * xi;
            acci += p * xi + q * xr;
        }
        out1[(size_t)bt * Fn + f] = make_float2(accr, acci);
        #pragma unroll
        for (int o = 0; o < On; ++o) {
            size_t wo = (size_t)(o * Fn + f) * Dn + dsel;
            out2[((size_t)bt * Fn + f) * On + o] = make_float2(wbr[wo], wbi[wo]);
        }
    }
}

extern "C" void kernel_launch(void* const* d_in, const int* in_sizes, int n_in,
                              void* d_out, int out_size, void* d_ws, size_t ws_size,
                              hipStream_t stream) {
    const float* Xr   = (const float*)d_in[0];
    const float* Xi   = (const float*)d_in[1];
    const float* tdoa = (const float*)d_in[2];
    const float2* dirs = (const float2*)d_in[3];
    const float* wcr = (const float*)d_in[4];
    const float* wci = (const float*)d_in[5];
    const float* wdr = (const float*)d_in[6];
    const float* wdi = (const float*)d_in[7];
    const float* wbr = (const float*)d_in[8];
    const float* wbi = (const float*)d_in[9];

    float* out = (float*)d_out;

    if (ws_size >= WS_NEEDED) {
        char* ws = (char*)d_ws;
        double* tab   = (double*)ws;
        double* bttab = (double*)(ws + TAB_BYTES);
        int* ind  = (int*)(ws + TAB_BYTES + BTT_PAD);
        int* boff = (int*)(ws + TAB_BYTES + BTT_PAD + IND_BYTES);
        int* bent = (int*)(ws + TAB_BYTES + BTT_PAD + IND_BYTES + BOFF_BYTES);

        build_tables<<<(Dn + BTn + 255) / 256, 256, 0, stream>>>(dirs, tdoa, tab, bttab);
        argmin_lds<<<BTn / 16, 256, 0, stream>>>(bttab, tab, ind);
        bucket_bts<<<1, 256, 0, stream>>>(ind, boff, bent);
        dim3 gcd(NCH, (Fn + FCH - 1) / FCH);   // 64 x 33
        fuse_cd<<<gcd, 256, 0, stream>>>(Xr, Xi, boff, bent, wcr, wci, wdr, wdi,
                                         out, out + OUT0_F);
        dim3 gb(NCH, (Fn + FCB - 1) / FCB);    // 64 x 11
        fuse_b<<<gb, 256, 0, stream>>>(boff, bent, wbr, wbi, out + OUT0_F + OUT1_F);
    } else {
        main_direct<<<BTn, 256, 0, stream>>>(Xr, Xi, tdoa, dirs,
                                             wcr, wci, wdr, wdi, wbr, wbi,
                                             (float2*)out,
                                             (float2*)(out + OUT0_F),
                                             (float2*)(out + OUT0_F + OUT1_F));
    }
}

// Round 11
// 60.971 us; speedup vs baseline: 1.8231x; 1.1426x over previous
//
#include <hip/hip_runtime.h>
#include <math.h>

typedef float f4v __attribute__((ext_vector_type(4)));
typedef float f2v __attribute__((ext_vector_type(2)));

// Problem constants (from reference setup_inputs)
constexpr int Bn = 4, Tn = 1000, Fn = 257, Cn = 6, Dn = 2048, On = 2;
constexpr int BTn = Bn * Tn;                      // 4000
constexpr double DEG2RAD = 0.017453292519943295;  // pi/180 in double

// Output segment offsets (in floats) within d_out
constexpr size_t OUT0_F = (size_t)BTn * Fn * Cn * 2;  // 12,336,000
constexpr size_t OUT1_F = (size_t)BTn * Fn * 2;       //  2,056,000

// d-chunking for the fused gather kernel
constexpr int DCH = 32;          // dirs per chunk
constexpr int NCH = Dn / DCH;    // 64 chunks
constexpr int FCH = 8;           // f per chunk (cd path)
constexpr int RWS = FCH * Cn;    // 48 rows
constexpr int FCB = 24;          // f per chunk (b path)
constexpr int RWB = FCB * On;    // 48 rows
constexpr int YCD = (Fn + FCH - 1) / FCH;  // 33
constexpr int YB  = (Fn + FCB - 1) / FCB;  // 11

// Workspace layout (bytes)
constexpr size_t TAB_BYTES  = (size_t)4 * Dn * sizeof(double);   // 65,536
constexpr size_t BTT_PAD    = 131072;                            // 4000*4 doubles padded
constexpr size_t IND_BYTES  = 16384;                             // 4000 ints padded
constexpr size_t BOFF_BYTES = 4096;                              // 65 ints padded
constexpr size_t BENT_BYTES = 16384;                             // 4000 ints padded
constexpr size_t WS_NEEDED  = TAB_BYTES + BTT_PAD + IND_BYTES + BOFF_BYTES + BENT_BYTES;

// ---------------------------------------------------------------------------
// K0: trig tables in double (verified bit-exact vs np in R4/R7).
// ---------------------------------------------------------------------------
__global__ __launch_bounds__(256) void build_tables(const float2* __restrict__ dirs,
                                                    const float* __restrict__ tdoa,
                                                    double* __restrict__ tab,
                                                    double* __restrict__ bttab) {
    int id = blockIdx.x * 256 + threadIdx.x;
    if (id < Dn) {
        float2 dr = dirs[id];
        double d0 = (double)dr.x, d1 = (double)dr.y;
        tab[0 * Dn + id] = cos(d0);
        tab[1 * Dn + id] = sin(d0);
        tab[2 * Dn + id] = cos(d1);
        tab[3 * Dn + id] = sin(d1);
    } else if (id < Dn + BTn) {
        int bt = id - Dn;
        double t0 = DEG2RAD * (double)tdoa[bt * 2 + 0];
        double t1 = DEG2RAD * (double)tdoa[bt * 2 + 1];
        bttab[bt * 4 + 0] = cos(t0);
        bttab[bt * 4 + 1] = sin(t0);
        bttab[bt * 4 + 2] = cos(t1);
        bttab[bt * 4 + 3] = sin(t1);
    }
}

// ---------------------------------------------------------------------------
// K1: argmin over direction codebook (verified passing R7/R9/R10, unchanged).
// ---------------------------------------------------------------------------
__global__ __launch_bounds__(256) void argmin_lds(const double* __restrict__ bttab,
                                                  const double* __restrict__ tab,
                                                  int* __restrict__ ind) {
    __shared__ double s_cd0[Dn];
    __shared__ double s_sd0[Dn];
    __shared__ double s_cd1[Dn];
    __shared__ double s_sd1[Dn];
    const int t = threadIdx.x;
    #pragma unroll
    for (int k = 0; k < Dn / 256; ++k) {
        int d = t + 256 * k;
        s_cd0[d] = tab[0 * Dn + d];
        s_sd0[d] = tab[1 * Dn + d];
        s_cd1[d] = tab[2 * Dn + d];
        s_sd1[d] = tab[3 * Dn + d];
    }
    __syncthreads();
    const int w = t >> 6, lane = t & 63;
    #pragma unroll
    for (int s = 0; s < 4; ++s) {
        const int bt = blockIdx.x * 16 + w * 4 + s;
        double ct0 = bttab[bt * 4 + 0], st0 = bttab[bt * 4 + 1];
        double ct1 = bttab[bt * 4 + 2], st1 = bttab[bt * 4 + 3];
        double best = 1e300;
        int bidx = 0;
        for (int i = 0; i < Dn / 256; ++i) {
            const int d0 = lane + 256 * i;
            double a[4];
            #pragma unroll
            for (int k = 0; k < 4; ++k) {
                int d = d0 + 64 * k;
                double u  = ct1 * s_cd1[d];
                double m1 = 1.0 - (u + st1 * s_sd1[d]);
                double m0 = 1.0 - (ct0 * s_cd0[d] + st0 * s_sd0[d]);
                a[k] = m1 + u * m0;
            }
            #pragma unroll
            for (int k = 0; k < 4; ++k) {
                int d = d0 + 64 * k;
                if (a[k] < best) { best = a[k]; bidx = d; }
            }
        }
        #pragma unroll
        for (int off = 32; off > 0; off >>= 1) {
            double ov = __shfl_down(best, off);
            int oi = __shfl_down(bidx, off);
            if (ov < best || (ov == best && oi < bidx)) { best = ov; bidx = oi; }
        }
        if (lane == 0) ind[bt] = bidx;
    }
}

// ---------------------------------------------------------------------------
// K2: bucket bts by 32-wide d-chunk (verified R10, unchanged).
// ---------------------------------------------------------------------------
__global__ __launch_bounds__(256) void bucket_bts(const int* __restrict__ ind,
                                                  int* __restrict__ boff,
                                                  int* __restrict__ bent) {
    __shared__ int cnts[NCH];
    __shared__ int curs[NCH];
    const int t = threadIdx.x;
    if (t < NCH) cnts[t] = 0;
    __syncthreads();
    #pragma unroll
    for (int k = 0; k < (BTn + 255) / 256; ++k) {
        int bt = k * 256 + t;
        if (bt < BTn) atomicAdd(&cnts[ind[bt] >> 5], 1);
    }
    __syncthreads();
    if (t == 0) {
        int acc = 0;
        for (int i = 0; i < NCH; ++i) { curs[i] = acc; boff[i] = acc; acc += cnts[i]; }
        boff[NCH] = acc;
    }
    __syncthreads();
    #pragma unroll
    for (int k = 0; k < (BTn + 255) / 256; ++k) {
        int bt = k * 256 + t;
        if (bt < BTn) {
            int d = ind[bt];
            int p = atomicAdd(&curs[d >> 5], 1);
            bent[p] = (bt << 5) | (d & 31);
        }
    }
}

// ---------------------------------------------------------------------------
// K3: fused gather-multiply, cd + b paths in one dispatch.
//   blockIdx.y < YCD : wc/wd tiles -> out0, out1  (X prefetched in registers
//                      BEFORE staging so HBM latency hides under it; T14)
//   blockIdx.y >= YCD: wb tile -> out2 panel copy (fills cd tail)
// LDS: 26112 B union -> 6 blocks/CU ceiling.
// ---------------------------------------------------------------------------
__global__ __launch_bounds__(256) void fuse_all(
    const float* __restrict__ Xr, const float* __restrict__ Xi,
    const int* __restrict__ boff, const int* __restrict__ bent,
    const float* __restrict__ wcr, const float* __restrict__ wci,
    const float* __restrict__ wdr, const float* __restrict__ wdi,
    const float* __restrict__ wbr, const float* __restrict__ wbi,
    float* __restrict__ out0, float* __restrict__ out1, float* __restrict__ out2) {
    __shared__ __align__(16) char smem[2 * RWS * 34 * sizeof(f2v)];
    const int bx = blockIdx.x;
    const int d0 = bx * DCH;
    const int t = threadIdx.x;
    const int off = boff[bx];
    const int cnt = boff[bx + 1] - off;

    if (blockIdx.y < YCD) {
        // ------------------------- cd path -------------------------
        f2v (*tc)[34] = (f2v(*)[34])smem;
        f2v (*td)[34] = (f2v(*)[34])(smem + sizeof(f2v) * RWS * 34);
        const int f0 = blockIdx.y * FCH;
        const int items = cnt * FCH;

        // ---- prefetch batch-0 X into registers (independent of staging) ----
        bool vA = false; int btA = 0, fA = 0, dlA = 0, rbA = 0;
        f2v xrA0 = {0,0}, xrA1 = {0,0}, xrA2 = {0,0};
        f2v xiA0 = {0,0}, xiA1 = {0,0}, xiA2 = {0,0};
        if (t < items) {
            int e = bent[off + (t >> 3)];
            int fi = t & 7, f = f0 + fi;
            if (f < Fn) {
                vA = true; btA = e >> 5; fA = f; dlA = e & 31; rbA = fi * Cn;
                size_t xb = ((size_t)btA * Fn + f) * Cn;
                const f2v* xr2 = (const f2v*)(Xr + xb);
                const f2v* xi2 = (const f2v*)(Xi + xb);
                xrA0 = xr2[0]; xrA1 = xr2[1]; xrA2 = xr2[2];
                xiA0 = xi2[0]; xiA1 = xi2[1]; xiA2 = xi2[2];
            }
        }
        // ---- stage wc & wd tiles (cached loads; L3 serves across replays) ----
        #pragma unroll
        for (int j = 0; j < 3; ++j) {
            int idx = j * 256 + t;
            const int pair = (idx >= 384) ? 1 : 0;
            int k = idx - pair * 384;
            int r = k >> 3, q4 = k & 7;
            int fi = r / Cn, c = r - fi * Cn;
            int f = f0 + fi;
            if (f < Fn) {
                size_t s = (size_t)(c * Fn + f) * Dn + d0 + 4 * q4;
                f4v vr = *(const f4v*)((pair ? wdr : wcr) + s);
                f4v vi = *(const f4v*)((pair ? wdi : wci) + s);
                f4v* trow = (f4v*)&(pair ? td : tc)[r][0];
                f4v lo = {vr[0], vi[0], vr[1], vi[1]};
                f4v hi = {vr[2], vi[2], vr[3], vi[3]};
                trow[2 * q4]     = lo;
                trow[2 * q4 + 1] = hi;
            }
        }
        __syncthreads();

        // ---- item loop with next-batch X prefetch ----
        for (int base = 0; base < items; base += 256) {
            bool vB = false; int btB = 0, fB = 0, dlB = 0, rbB = 0;
            f2v xrB0 = {0,0}, xrB1 = {0,0}, xrB2 = {0,0};
            f2v xiB0 = {0,0}, xiB1 = {0,0}, xiB2 = {0,0};
            int itn = base + 256 + t;
            if (itn < items) {
                int e = bent[off + (itn >> 3)];
                int fi = itn & 7, f = f0 + fi;
                if (f < Fn) {
                    vB = true; btB = e >> 5; fB = f; dlB = e & 31; rbB = fi * Cn;
                    size_t xb = ((size_t)btB * Fn + f) * Cn;
                    const f2v* xr2 = (const f2v*)(Xr + xb);
                    const f2v* xi2 = (const f2v*)(Xi + xb);
                    xrB0 = xr2[0]; xrB1 = xr2[1]; xrB2 = xr2[2];
                    xiB0 = xi2[0]; xiB1 = xi2[1]; xiB2 = xi2[2];
                }
            }
            if (vA) {
                float xr[Cn] = {xrA0[0], xrA0[1], xrA1[0], xrA1[1], xrA2[0], xrA2[1]};
                float xi[Cn] = {xiA0[0], xiA0[1], xiA1[0], xiA1[1], xiA2[0], xiA2[1]};
                float o0[Cn * 2];
                float accr = 0.f, acci = 0.f;
                #pragma unroll
                for (int c = 0; c < Cn; ++c) {
                    f2v wcv = tc[rbA + c][dlA];
                    f2v wdv = td[rbA + c][dlA];
                    o0[2 * c]     = wdv[0] * xr[c] - wdv[1] * xi[c];
                    o0[2 * c + 1] = wdv[0] * xi[c] + wdv[1] * xr[c];
                    accr += wcv[0] * xr[c] - wcv[1] * xi[c];
                    acci += wcv[0] * xi[c] + wcv[1] * xr[c];
                }
                size_t xb = ((size_t)btA * Fn + fA) * Cn;
                f4v* ob = (f4v*)(out0 + xb * 2);          // 48B-multiple -> 16B aligned
                f4v p0 = {o0[0], o0[1], o0[2], o0[3]};
                f4v p1 = {o0[4], o0[5], o0[6], o0[7]};
                f4v p2 = {o0[8], o0[9], o0[10], o0[11]};
                ob[0] = p0; ob[1] = p1; ob[2] = p2;       // cached: L2 merges lines
                f2v o1 = {accr, acci};
                ((f2v*)out1)[(size_t)btA * Fn + fA] = o1;
            }
            vA = vB; btA = btB; fA = fB; dlA = dlB; rbA = rbB;
            xrA0 = xrB0; xrA1 = xrB1; xrA2 = xrB2;
            xiA0 = xiB0; xiA1 = xiB1; xiA2 = xiB2;
        }
    } else {
        // ------------------------- b path -------------------------
        f2v (*tb)[34] = (f2v(*)[34])smem;
        const int f0 = (blockIdx.y - YCD) * FCB;
        #pragma unroll
        for (int j = 0; j < 2; ++j) {   // 48 rows x 8 f4 = 384 items
            int idx = j * 256 + t;
            if (idx < RWB * 8) {
                int r = idx >> 3, q4 = idx & 7;
                int fi = r >> 1, o = r & 1;
                int f = f0 + fi;
                if (f < Fn) {
                    size_t s = (size_t)(o * Fn + f) * Dn + d0 + 4 * q4;
                    f4v vr = *(const f4v*)(wbr + s);
                    f4v vi = *(const f4v*)(wbi + s);
                    f4v* trow = (f4v*)&tb[r][0];
                    f4v lo = {vr[0], vi[0], vr[1], vi[1]};
                    f4v hi = {vr[2], vi[2], vr[3], vi[3]};
                    trow[2 * q4]     = lo;
                    trow[2 * q4 + 1] = hi;
                }
            }
        }
        __syncthreads();
        const int items = cnt * FCB;
        for (int base = 0; base < items; base += 256) {
            int it = base + t;
            if (it < items) {
                int m = it / FCB, fi = it - m * FCB;
                int e = bent[off + m];
                int bt = e >> 5, dl = e & 31;
                int f = f0 + fi;
                if (f < Fn) {
                    f2v a = tb[fi * 2][dl];
                    f2v b = tb[fi * 2 + 1][dl];
                    f4v o2 = {a[0], a[1], b[0], b[1]};
                    ((f4v*)out2)[(size_t)bt * Fn + f] = o2;
                }
            }
        }
    }
}

// Fallback (no workspace): direct strided gather, per-block argmin
__global__ __launch_bounds__(256) void main_direct(
    const float* __restrict__ Xr, const float* __restrict__ Xi,
    const float* __restrict__ tdoa, const float2* __restrict__ dirs,
    const float* __restrict__ wcr, const float* __restrict__ wci,
    const float* __restrict__ wdr, const float* __restrict__ wdi,
    const float* __restrict__ wbr, const float* __restrict__ wbi,
    float2* __restrict__ out0, float2* __restrict__ out1, float2* __restrict__ out2) {
    const int bt = blockIdx.x;
    const int tid = threadIdx.x;
    __shared__ double sv[256];
    __shared__ int si[256];

    double t0 = DEG2RAD * (double)tdoa[bt * 2 + 0];
    double t1 = DEG2RAD * (double)tdoa[bt * 2 + 1];
    double ct1 = cos(t1);
    double best = 1e300;
    int bidx = 0;
    for (int d = tid; d < Dn; d += 256) {
        float2 dr = dirs[d];
        double s1 = sin(0.5 * (t1 - (double)dr.y));
        double s2 = sin(0.5 * (t0 - (double)dr.x));
        double a = s1 * s1 + ct1 * cos((double)dr.y) * (s2 * s2);
        if (a < best) { best = a; bidx = d; }
    }
    sv[tid] = best; si[tid] = bidx;
    __syncthreads();
    for (int s = 128; s > 0; s >>= 1) {
        if (tid < s) {
            double v = sv[tid + s]; int j = si[tid + s];
            if (v < sv[tid] || (v == sv[tid] && j < si[tid])) { sv[tid] = v; si[tid] = j; }
        }
        __syncthreads();
    }
    const int dsel = si[0];
    const size_t base = (size_t)bt * Fn * Cn;

    for (int f = tid; f < Fn; f += 256) {
        const int fc = f * Cn;
        float accr = 0.f, acci = 0.f;
        #pragma unroll
        for (int c = 0; c < Cn; ++c) {
            float xr = Xr[base + fc + c], xi = Xi[base + fc + c];
            size_t wo = (size_t)(c * Fn + f) * Dn + dsel;
            float a_ = wdr[wo], b_ = wdi[wo];
            out0[base + fc + c] = make_float2(a_ * xr - b_ * xi, a_ * xi + b_ * xr);
            float p = wcr[wo], q = wci[wo];
            accr += p * xr - q * xi;
            acci += p * xi + q * xr;
        }
        out1[(size_t)bt * Fn + f] = make_float2(accr, acci);
        #pragma unroll
        for (int o = 0; o < On; ++o) {
            size_t wo = (size_t)(o * Fn + f) * Dn + dsel;
            out2[((size_t)bt * Fn + f) * On + o] = make_float2(wbr[wo], wbi[wo]);
        }
    }
}

extern "C" void kernel_launch(void* const* d_in, const int* in_sizes, int n_in,
                              void* d_out, int out_size, void* d_ws, size_t ws_size,
                              hipStream_t stream) {
    const float* Xr   = (const float*)d_in[0];
    const float* Xi   = (const float*)d_in[1];
    const float* tdoa = (const float*)d_in[2];
    const float2* dirs = (const float2*)d_in[3];
    const float* wcr = (const float*)d_in[4];
    const float* wci = (const float*)d_in[5];
    const float* wdr = (const float*)d_in[6];
    const float* wdi = (const float*)d_in[7];
    const float* wbr = (const float*)d_in[8];
    const float* wbi = (const float*)d_in[9];

    float* out = (float*)d_out;

    if (ws_size >= WS_NEEDED) {
        char* ws = (char*)d_ws;
        double* tab   = (double*)ws;
        double* bttab = (double*)(ws + TAB_BYTES);
        int* ind  = (int*)(ws + TAB_BYTES + BTT_PAD);
        int* boff = (int*)(ws + TAB_BYTES + BTT_PAD + IND_BYTES);
        int* bent = (int*)(ws + TAB_BYTES + BTT_PAD + IND_BYTES + BOFF_BYTES);

        build_tables<<<(Dn + BTn + 255) / 256, 256, 0, stream>>>(dirs, tdoa, tab, bttab);
        argmin_lds<<<BTn / 16, 256, 0, stream>>>(bttab, tab, ind);
        bucket_bts<<<1, 256, 0, stream>>>(ind, boff, bent);
        dim3 g(NCH, YCD + YB);   // 64 x 44
        fuse_all<<<g, 256, 0, stream>>>(Xr, Xi, boff, bent,
                                        wcr, wci, wdr, wdi, wbr, wbi,
                                        out, out + OUT0_F, out + OUT0_F + OUT1_F);
    } else {
        main_direct<<<BTn, 256, 0, stream>>>(Xr, Xi, tdoa, dirs,
                                             wcr, wci, wdr, wdi, wbr, wbi,
                                             (float2*)out,
                                             (float2*)(out + OUT0_F),
                                             (float2*)(out + OUT0_F + OUT1_F));
    }
}